// Round 10
// baseline (160.262 us; speedup 1.0000x reference)
//
#include <hip/hip_runtime.h>
#include <math.h>

// ClownSelector R10: R9 pipeline at 2x occupancy (4 waves/SIMD).
//
// R9 post-mortem: no spill, but VALUBusy 28% with only 2 waves/SIMD (grid
// 512 = 2 blocks/CU was the binding constraint; VGPR 128 allows 4/SIMD).
// R10: block = 16 tokens x 4 waves (k-slice 256 each), grid 1024 = 4
// blocks/CU = 4 waves/SIMD. Thread tile 2tok x 8exp (16 acc, VGPR ~85).
// Per k-step: 1 ds_read_b64 (8 distinct bank-pairs, 8-way broadcast dedup,
// conflict-free) + 2 rotated proto quads (depth-4 register rotation, L2-hot)
// + 16 v_fmac. x staging double-buffered through registers; wave-private
// LDS, DS in-order -> zero barriers in the K-loop. Rotation tail clamp
// dropped: the 4 dead prefetches past the slice read into the ws dots
// region (valid memory, values never consumed).
// Reduction tree, fused norm, K0, K2: R7/R9-verified, unchanged in math.

#define BB 8
#define SS 2048
#define DD 1024
#define EE 64
#define EPSV 1e-8f

#define FMA4(A, s, P) \
  A.x += (s) * (P).x; A.y += (s) * (P).y; A.z += (s) * (P).z; A.w += (s) * (P).w;

#define SUMSQ4(v) ((v).x * (v).x + (v).y * (v).y + (v).z * (v).z + (v).w * (v).w)

// ---- K0: proto[e][d] -> ptt[d][e] -----------------------------------------
__global__ __launch_bounds__(256) void repack_proto(
    const float* __restrict__ proto, float* __restrict__ ptt) {
  const int gid = blockIdx.x * 256 + threadIdx.x;  // 0..65535
  const int d = gid >> 6;
  const int e = gid & 63;
  ptt[gid] = proto[(size_t)e * DD + d];
}

// ---- K1: normalized per-row dots ------------------------------------------
__global__ __launch_bounds__(256, 2) void router_dots(
    const float* __restrict__ x, const float* __restrict__ ptt,
    float* __restrict__ dots) {
  __shared__ float xt[4][2][16][18];  // per-wave dbuf x chunk [k][tok], 9216 B
  __shared__ float B0[16][68];        // reduction buffers
  __shared__ float B1[16][68];
  __shared__ float nq[4][16];         // per-wave per-token sumsq partials

  const int lane = threadIdx.x & 63;
  const int w    = __builtin_amdgcn_readfirstlane(threadIdx.x >> 6);
  const int b    = blockIdx.x >> 7;            // 128 blocks per batch
  const int s0   = (blockIdx.x & 127) * 16;    // 16 tokens per block

  const int toks = lane & 15;  // staging: token
  const int kq   = lane >> 4;  // staging: k-quarter (4 floats)
  const int eg   = lane & 7;   // tile: expert group (8 e)
  const int tg   = lane >> 3;  // tile: token pair (2 t)

  const float* xb = x + ((size_t)b * SS + s0) * DD;
  const int kbase = w * 256;   // this wave's k-slice

  float4 acc0[2], acc1[2];
#pragma unroll
  for (int i = 0; i < 2; ++i) {
    acc0[i] = make_float4(0.f, 0.f, 0.f, 0.f);
    acc1[i] = make_float4(0.f, 0.f, 0.f, 0.f);
  }
  float q = 0.0f;

  // ---- preload + stage chunk 0 into buf 0 ----
  {
    const float4 va = *(const float4*)(xb + (size_t)toks * DD + kbase + kq * 4);
    q += SUMSQ4(va);
    float* dstc = &xt[w][0][0][toks];
    dstc[(kq * 4 + 0) * 18] = va.x;
    dstc[(kq * 4 + 1) * 18] = va.y;
    dstc[(kq * 4 + 2) * 18] = va.z;
    dstc[(kq * 4 + 3) * 18] = va.w;
  }

  // ---- proto rotation preload: k = kbase..kbase+3 ----
  float4 pp0[4], pp1[4];
#pragma unroll
  for (int r = 0; r < 4; ++r) {
    const float* pr = ptt + (size_t)(kbase + r) * EE + eg * 8;
    pp0[r] = *(const float4*)(pr);
    pp1[r] = *(const float4*)(pr + 4);
  }

  for (int c = 0; c < 16; ++c) {   // 16 chunks x 16 k = 256 k
    const int cur = c & 1;
    // ---- prefetch next chunk's x (consumed after the k-loop) ----
    float4 na;
    if (c + 1 < 16) {
      na = *(const float4*)(xb + (size_t)toks * DD + kbase + (c + 1) * 16 + kq * 4);
    }
    // ---- 16 k-steps: ds_read_b64 x-pair + rotated proto + 16 fmac ----
#pragma unroll
    for (int kk = 0; kk < 16; ++kk) {
      const int slot = kk & 3;
      const float2 xf = *(const float2*)(&xt[w][cur][kk][tg * 2]);
      const float4 p0 = pp0[slot];
      const float4 p1 = pp1[slot];
      // continuous rotation; tail prefetches land in ws (dead values)
      const int kpre = kbase + c * 16 + kk + 4;
      const float* pr = ptt + (size_t)kpre * EE + eg * 8;
      pp0[slot] = *(const float4*)(pr);
      pp1[slot] = *(const float4*)(pr + 4);
      FMA4(acc0[0], xf.x, p0) FMA4(acc1[0], xf.x, p1)
      FMA4(acc0[1], xf.y, p0) FMA4(acc1[1], xf.y, p1)
    }
    // ---- stage prefetched chunk into the other buffer ----
    if (c + 1 < 16) {
      q += SUMSQ4(na);
      float* dstc = &xt[w][cur ^ 1][0][toks];
      dstc[(kq * 4 + 0) * 18] = na.x;
      dstc[(kq * 4 + 1) * 18] = na.y;
      dstc[(kq * 4 + 2) * 18] = na.z;
      dstc[(kq * 4 + 3) * 18] = na.w;
    }
  }

  // sumsq: combine the 4 k-quarters of each token; kq==0 lanes publish
  q += __shfl_xor(q, 16);
  q += __shfl_xor(q, 32);
  if (kq == 0) nq[w][toks] = q;

#define WRB(R)                                                  \
  { _Pragma("unroll") for (int i = 0; i < 2; ++i) {             \
      *(float4*)(&(R)[tg * 2 + i][eg * 8])     = acc0[i];       \
      *(float4*)(&(R)[tg * 2 + i][eg * 8 + 4]) = acc1[i]; } }
#define ADDB(R)                                                 \
  { _Pragma("unroll") for (int i = 0; i < 2; ++i) {             \
      const float4 t0 = *(const float4*)(&(R)[tg * 2 + i][eg * 8]);     \
      const float4 t1 = *(const float4*)(&(R)[tg * 2 + i][eg * 8 + 4]); \
      acc0[i].x += t0.x; acc0[i].y += t0.y;                     \
      acc0[i].z += t0.z; acc0[i].w += t0.w;                     \
      acc1[i].x += t1.x; acc1[i].y += t1.y;                     \
      acc1[i].z += t1.z; acc1[i].w += t1.w; } }

  // deterministic tree: ((w0+w1) + (w2+w3))
  __syncthreads();
  if (w == 1) WRB(B0)
  if (w == 3) WRB(B1)
  __syncthreads();
  if (w == 0) ADDB(B0)
  if (w == 2) ADDB(B1)
  __syncthreads();
  if (w == 2) WRB(B0)
  __syncthreads();
  if (w == 0) {
    ADDB(B0)
#pragma unroll
    for (int i = 0; i < 2; ++i) {
      const int row = tg * 2 + i;
      const float qs = nq[0][row] + nq[1][row] + nq[2][row] + nq[3][row];
      const float inv = 1.0f / fmaxf(sqrtf(qs), EPSV);
      float4 o0, o1;
      o0.x = acc0[i].x * inv; o0.y = acc0[i].y * inv;
      o0.z = acc0[i].z * inv; o0.w = acc0[i].w * inv;
      o1.x = acc1[i].x * inv; o1.y = acc1[i].y * inv;
      o1.z = acc1[i].z * inv; o1.w = acc1[i].w * inv;
      float* dp = dots + ((size_t)b * SS + s0 + row) * EE + eg * 8;
      *(float4*)(dp)     = o0;
      *(float4*)(dp + 4) = o1;
    }
  }
}

// ---- K2: window-3 + top-2 + renorm softmax (array-free, R7-verified) -------
#define T2UP(s, ei)                                            \
  if ((s) > v1) { v2 = v1; i2 = i1; v1 = (s); i1 = (ei); }     \
  else if ((s) > v2) { v2 = (s); i2 = (ei); }

__global__ __launch_bounds__(256) void router_top2(
    const float* __restrict__ dots, float* __restrict__ out) {
  const int gtid = blockIdx.x * 256 + threadIdx.x;  // 0..32767
  const int tok  = gtid >> 1;          // global token
  const int h    = gtid & 1;           // expert half (32 each)
  const int b    = tok >> 11;
  const int sl   = tok & (SS - 1);
  const int r0   = (sl >= 2) ? sl - 2 : 0;   // causal pad: replicate token 0
  const int r1   = (sl >= 1) ? sl - 1 : 0;

  const float* d0 = dots + ((size_t)b * SS + r0) * EE + h * 32;
  const float* d1 = dots + ((size_t)b * SS + r1) * EE + h * 32;
  const float* d2 = dots + ((size_t)b * SS + sl) * EE + h * 32;

  float v1 = -INFINITY, v2 = -INFINITY;
  int i1 = 0, i2 = 0;
#pragma unroll
  for (int qd = 0; qd < 8; ++qd) {
    const float4 a = *(const float4*)(d0 + qd * 4);
    const float4 c = *(const float4*)(d1 + qd * 4);
    const float4 e = *(const float4*)(d2 + qd * 4);
    const int e0 = h * 32 + qd * 4;
    float s;
    s = a.x + c.x + e.x; T2UP(s, e0 + 0)
    s = a.y + c.y + e.y; T2UP(s, e0 + 1)
    s = a.z + c.z + e.z; T2UP(s, e0 + 2)
    s = a.w + c.w + e.w; T2UP(s, e0 + 3)
  }

  {  // merge the two halves (partner lane = lane^1); tie -> lower index
    const float ov1 = __shfl_xor(v1, 1);
    const int   oi1 = __shfl_xor(i1, 1);
    const float ov2 = __shfl_xor(v2, 1);
    const int   oi2 = __shfl_xor(i2, 1);
    const bool o_beats = (ov1 > v1) || (ov1 == v1 && oi1 < i1);
    if (o_beats) {
      const bool v1_beats_o2 = (v1 > ov2) || (v1 == ov2 && i1 < oi2);
      v2 = v1_beats_o2 ? v1 : ov2;
      i2 = v1_beats_o2 ? i1 : oi2;
      v1 = ov1;
      i1 = oi1;
    } else {
      const bool o1_beats_v2 = (ov1 > v2) || (ov1 == v2 && oi1 < i2);
      if (o1_beats_v2) { v2 = ov1; i2 = oi1; }
    }
  }

  if (h == 0) {
    const float ex = expf((v2 - v1) * (1.0f / 3.0f));  // <= 1
    const float w1 = 1.0f / (1.0f + ex);
    const size_t o = (size_t)tok * 2;
    *(float2*)(out + o) = make_float2((float)i1, (float)i2);
    *(float2*)(out + (size_t)BB * SS * 2 + o) = make_float2(w1, ex * w1);
  }
}

extern "C" void kernel_launch(void* const* d_in, const int* in_sizes, int n_in,
                              void* d_out, int out_size, void* d_ws, size_t ws_size,
                              hipStream_t stream) {
  const float* x     = (const float*)d_in[0];
  const float* proto = (const float*)d_in[1];
  // d_in[2] = attn_mask: unused by the reference output path.
  float* out  = (float*)d_out;
  float* ptt  = (float*)d_ws;                          // 256 KiB ptt[d][e]
  float* dots = (float*)((char*)d_ws + (512 << 10));   // 4 MiB normalized dots

  repack_proto<<<dim3(256), dim3(256), 0, stream>>>(proto, ptt);
  router_dots<<<dim3(1024), dim3(256), 0, stream>>>(x, ptt, dots);
  router_top2<<<dim3(128), dim3(256), 0, stream>>>(dots, out);
}